// Round 2
// baseline (574.496 us; speedup 1.0000x reference)
//
#include <hip/hip_runtime.h>
#include <hip/hip_bf16.h>
#include <math.h>

#define NN 128
#define TRI 8256          // 128*129/2
#define BATCH 2048
#define M_L 10
#define KAPPA 0.276f

// ---------------------------------------------------------------------------
// Kernel 1: per-batch Lanczos (one block of 128 threads per batch).
// L (packed lower-tri, row-major == net_out layout) staged in LDS once,
// 10 Lanczos iterations in-block. Writes alphas[10] + betas[10] per batch.
// ---------------------------------------------------------------------------
__global__ __launch_bounds__(128) void lanczos_kernel(
    const float* __restrict__ net_out,
    const float* __restrict__ U1,
    const float* __restrict__ v_in,
    float* __restrict__ ab_out)   // [BATCH][20]
{
    __shared__ __align__(16) float Lt[TRI];
    __shared__ float u0s[64];
    __shared__ float u1s[64];
    __shared__ __align__(16) float xv[NN];   // current Lanczos vector
    __shared__ __align__(16) float yv[NN];   // dd output
    __shared__ __align__(16) float y2v[NN];  // L^T * yv
    __shared__ float red[4];

    const int b = blockIdx.x;
    const int t = threadIdx.x;
    const int lane = t & 63;
    const int wv = t >> 6;

    // ---- stage L into LDS (float4 coalesced) ----
    {
        const float4* src = (const float4*)(net_out + (size_t)b * TRI);
        float4* dst = (float4*)Lt;
        for (int k = t; k < TRI / 4; k += 128) dst[k] = src[k];
    }
    // ---- stage U1 gauge links ----
    if (t < 64) {
        const float2* uu = (const float2*)(U1 + (size_t)b * 128);
        float2 p = uu[t];
        u0s[t] = p.x;
        u1s[t] = p.y;
    }

    // ---- load v, normalize ----
    float vt = v_in[(size_t)b * NN + t];
    float s = vt * vt;
    #pragma unroll
    for (int o = 32; o > 0; o >>= 1) s += __shfl_down(s, o, 64);
    if (lane == 0) red[wv] = s;
    __syncthreads();
    float nrm = sqrtf(red[0] + red[1]);
    xv[t] = vt / nrm;
    float pvf = 0.0f;   // v_prev element (thread-local)
    __syncthreads();

    float beta = 0.0f;

    // precompute dd stencil indices for this thread
    const int si = t >> 4, sj = (t >> 1) & 7, ss = t & 1;
    const int ip = (si + 1) & 7, im = (si + 7) & 7;
    const int jp = (sj + 1) & 7, jm = (sj + 7) & 7;
    const int idx_ip = (ip << 4) | (sj << 1) | ss;
    const int idx_jp = (si << 4) | (jp << 1) | ss;
    const int idx_im = (im << 4) | (sj << 1) | ss;
    const int idx_jm = (si << 4) | (jm << 1) | ss;

    for (int m = 0; m < M_L; m++) {
        // ---- dd_opt: y = x - kappa * hop ----
        float x_t = xv[t];
        float hop = u0s[si * 8 + sj] * xv[idx_ip]
                  + u1s[si * 8 + sj] * xv[idx_jp]
                  + u0s[im * 8 + sj] * xv[idx_im]
                  + u1s[si * 8 + jm] * xv[idx_jm];
        yv[t] = x_t - KAPPA * hop;
        __syncthreads();

        // ---- y2 = L^T * y :  y2[t] = sum_{i>=t} L[i][t] * y[i] ----
        // uniform loop over i; lane t reads column t -> stride-1 across lanes
        {
            float acc = 0.0f;
            const float4* yv4 = (const float4*)yv;
            int tri = 0;   // tri(i0) = i0*(i0+1)/2
            #pragma unroll 4
            for (int c = 0; c < 32; c++) {
                const int i0 = 4 * c;
                float4 y4 = yv4[c];
                float l0 = Lt[tri + t];
                float l1 = Lt[tri + (i0 + 1) + t];
                float l2 = Lt[tri + (2 * i0 + 3) + t];
                float l3 = Lt[tri + (3 * i0 + 6) + t];
                if (i0     >= t) acc += l0 * y4.x;
                if (i0 + 1 >= t) acc += l1 * y4.y;
                if (i0 + 2 >= t) acc += l2 * y4.z;
                if (i0 + 3 >= t) acc += l3 * y4.w;
                tri += 4 * i0 + 10;
            }
            y2v[t] = acc;
        }
        __syncthreads();

        // ---- w = L * y2 :  w[t] = sum_{j<=t} L[t][j] * y2[j] ----
        float wacc = 0.0f;
        {
            const float4* y24 = (const float4*)y2v;
            const int base = t * (t + 1) / 2;
            const int cmax = t >> 2;   // last chunk index containing j<=t
            for (int c = 0; c <= cmax; c++) {
                const int j0 = 4 * c;
                float4 y4 = y24[c];
                if (j0     <= t) wacc += Lt[base + j0]     * y4.x;
                if (j0 + 1 <= t) wacc += Lt[base + j0 + 1] * y4.y;
                if (j0 + 2 <= t) wacc += Lt[base + j0 + 2] * y4.z;
                if (j0 + 3 <= t) wacc += Lt[base + j0 + 3] * y4.w;
            }
        }

        // ---- alpha = <w, v_cur> ----
        float xcur = xv[t];
        s = wacc * xcur;
        #pragma unroll
        for (int o = 32; o > 0; o >>= 1) s += __shfl_down(s, o, 64);
        if (lane == 0) red[wv] = s;
        __syncthreads();
        float alpha = red[0] + red[1];

        // ---- w -= alpha*v_cur + beta*v_prev ----
        wacc -= alpha * xcur + beta * pvf;

        // ---- beta_new = ||w|| ----
        s = wacc * wacc;
        #pragma unroll
        for (int o = 32; o > 0; o >>= 1) s += __shfl_down(s, o, 64);
        if (lane == 0) red[wv + 2] = s;
        __syncthreads();
        float beta_new = sqrtf(red[2] + red[3]);

        // ---- advance ----
        pvf = xcur;
        xv[t] = wacc / (beta_new + 1e-30f);
        beta = beta_new;

        if (t == 0) {
            ab_out[(size_t)b * 20 + m]      = alpha;
            ab_out[(size_t)b * 20 + 10 + m] = beta_new;
        }
        __syncthreads();
    }
}

// ---------------------------------------------------------------------------
// Kernel 2: per-batch eigenvalues of 10x10 symmetric tridiagonal via Sturm
// bisection (fp64).  contrib[b] = max|l|^2 - min|l|^2.
// ---------------------------------------------------------------------------
__device__ inline int sturm_count(const double* a, const double* off2, double x) {
    int c = 0;
    double q = a[0] - x;
    if (q < 0.0) c++;
    #pragma unroll
    for (int i = 1; i < M_L; i++) {
        double d = q;
        if (fabs(d) < 1e-300) d = (d < 0.0) ? -1e-300 : 1e-300;
        q = (a[i] - x) - off2[i - 1] / d;
        if (q < 0.0) c++;
    }
    return c;
}

__global__ __launch_bounds__(256) void eig_kernel(
    const float* __restrict__ ab, float* __restrict__ contrib)
{
    int b = blockIdx.x * blockDim.x + threadIdx.x;
    if (b >= BATCH) return;
    const float* p = ab + (size_t)b * 20;
    double a[M_L], off2[M_L - 1], offa[M_L - 1];
    #pragma unroll
    for (int i = 0; i < M_L; i++) a[i] = (double)p[i];
    #pragma unroll
    for (int i = 0; i < M_L - 1; i++) {
        double bb = (double)p[10 + i];
        offa[i] = fabs(bb);
        off2[i] = bb * bb;
    }
    // Gershgorin bounds
    double lo = 1e300, hi = -1e300;
    #pragma unroll
    for (int i = 0; i < M_L; i++) {
        double r = 0.0;
        if (i > 0) r += offa[i - 1];
        if (i < M_L - 1) r += offa[i];
        lo = fmin(lo, a[i] - r);
        hi = fmax(hi, a[i] + r);
    }
    // lambda_max
    double l = lo, h = hi;
    for (int it = 0; it < 60; it++) {
        double mid = 0.5 * (l + h);
        if (sturm_count(a, off2, mid) >= M_L) h = mid; else l = mid;
    }
    double lmax = 0.5 * (l + h);
    // lambda_min
    l = lo; h = hi;
    for (int it = 0; it < 60; it++) {
        double mid = 0.5 * (l + h);
        if (sturm_count(a, off2, mid) >= 1) h = mid; else l = mid;
    }
    double lmin = 0.5 * (l + h);
    double maxabs = fmax(fabs(lmax), fabs(lmin));
    // min |lambda| : smallest t with an eigenvalue in [-t, t)
    double tl = 0.0, th = maxabs;
    for (int it = 0; it < 60; it++) {
        double tm = 0.5 * (tl + th);
        int inwin = sturm_count(a, off2, tm) - sturm_count(a, off2, -tm);
        if (inwin >= 1) th = tm; else tl = tm;
    }
    double minabs = 0.5 * (tl + th);
    contrib[b] = (float)(maxabs * maxabs - minabs * minabs);
}

// ---------------------------------------------------------------------------
// Kernel 3: reduce 2048 contributions -> d_out[0] (mean)
// ---------------------------------------------------------------------------
__global__ __launch_bounds__(1024) void reduce_kernel(
    const float* __restrict__ contrib, float* __restrict__ out)
{
    __shared__ float red[16];
    int t = threadIdx.x;
    float s = contrib[t] + contrib[t + 1024];
    #pragma unroll
    for (int o = 32; o > 0; o >>= 1) s += __shfl_down(s, o, 64);
    if ((t & 63) == 0) red[t >> 6] = s;
    __syncthreads();
    if (t < 64) {
        float r = (t < 16) ? red[t] : 0.0f;
        #pragma unroll
        for (int o = 8; o > 0; o >>= 1) r += __shfl_down(r, o, 64);
        if (t == 0) out[0] = r / (float)BATCH;
    }
}

extern "C" void kernel_launch(void* const* d_in, const int* in_sizes, int n_in,
                              void* d_out, int out_size, void* d_ws, size_t ws_size,
                              hipStream_t stream) {
    const float* net_out = (const float*)d_in[0];
    const float* U1      = (const float*)d_in[1];
    const float* v       = (const float*)d_in[2];
    float* ab      = (float*)d_ws;            // BATCH*20 floats
    float* contrib = ab + (size_t)BATCH * 20; // BATCH floats

    lanczos_kernel<<<BATCH, 128, 0, stream>>>(net_out, U1, v, ab);
    eig_kernel<<<BATCH / 256, 256, 0, stream>>>(ab, contrib);
    reduce_kernel<<<1, 1024, 0, stream>>>(contrib, (float*)d_out);
}

// Round 3
// 291.301 us; speedup vs baseline: 1.9722x; 1.9722x over previous
//
#include <hip/hip_runtime.h>
#include <hip/hip_bf16.h>
#include <math.h>

#define NN 128
#define TRI 8256          // 128*129/2
#define BATCH 2048
#define M_L 10
#define KAPPA 0.276f

// ---------------------------------------------------------------------------
// Kernel 1: per-batch Lanczos. 256 threads per batch: each output element of
// the two triangular matvecs is computed by TWO threads (chunk-parity split),
// halving per-thread LDS chains and doubling waves/CU vs the 128-thread
// version (LDS ~36KB -> 4 blocks/CU -> 16 waves/CU).
// ---------------------------------------------------------------------------
__global__ __launch_bounds__(256) void lanczos_kernel(
    const float* __restrict__ net_out,
    const float* __restrict__ U1,
    const float* __restrict__ v_in,
    float* __restrict__ ab_out)   // [BATCH][20]
{
    __shared__ __align__(16) float Lt[TRI];
    __shared__ float u0s[64];
    __shared__ float u1s[64];
    __shared__ __align__(16) float xv[NN];   // current Lanczos vector
    __shared__ __align__(16) float yv[NN];   // dd output
    __shared__ __align__(16) float y2v[NN];  // L^T * yv
    __shared__ __align__(16) float part[256];
    __shared__ float red[4];

    const int b = blockIdx.x;
    const int t = threadIdx.x;
    const int tl = t & 127;       // element (column / row) owned
    const int h  = t >> 7;        // which half-partner (chunk parity)
    const int lane = t & 63;

    // ---- stage L into LDS (float4 coalesced, all 256 threads) ----
    {
        const float4* src = (const float4*)(net_out + (size_t)b * TRI);
        float4* dst = (float4*)Lt;
        for (int k = t; k < TRI / 4; k += 256) dst[k] = src[k];
    }
    // ---- stage U1 gauge links ----
    if (t < 64) {
        const float2* uu = (const float2*)(U1 + (size_t)b * 128);
        float2 p = uu[t];
        u0s[t] = p.x;
        u1s[t] = p.y;
    }

    // ---- load v, normalize (threads < 128) ----
    float pvf = 0.0f;
    if (t < 128) {
        float vt = v_in[(size_t)b * NN + t];
        float s = vt * vt;
        #pragma unroll
        for (int o = 32; o > 0; o >>= 1) s += __shfl_down(s, o, 64);
        if (lane == 0) red[t >> 6] = s;
        __syncthreads();
        float nrm = sqrtf(red[0] + red[1]);
        xv[t] = vt / nrm;
    } else {
        __syncthreads();
    }
    __syncthreads();

    float beta = 0.0f;

    // dd stencil indices (threads < 128 use them)
    const int si = tl >> 4, sj = (tl >> 1) & 7, ss = tl & 1;
    const int ip = (si + 1) & 7, im = (si + 7) & 7;
    const int jp = (sj + 1) & 7, jm = (sj + 7) & 7;
    const int idx_ip = (ip << 4) | (sj << 1) | ss;
    const int idx_jp = (si << 4) | (jp << 1) | ss;
    const int idx_im = (im << 4) | (sj << 1) | ss;
    const int idx_jm = (si << 4) | (jm << 1) | ss;

    for (int m = 0; m < M_L; m++) {
        // ---- dd_opt: y = x - kappa * hop (threads < 128) ----
        if (t < 128) {
            float x_t = xv[tl];
            float hop = u0s[si * 8 + sj] * xv[idx_ip]
                      + u1s[si * 8 + sj] * xv[idx_jp]
                      + u0s[im * 8 + sj] * xv[idx_im]
                      + u1s[si * 8 + jm] * xv[idx_jm];
            yv[tl] = x_t - KAPPA * hop;
        }
        __syncthreads();   // B1

        // ---- y2 = L^T * y : partner h takes chunks of parity h ----
        {
            float acc = 0.0f;
            const float4* yv4 = (const float4*)yv;
            const int c = tl;
            int i0  = 4 * h;                 // 0 or 4
            int tri = h ? 10 : 0;            // tri(i0) = i0*(i0+1)/2
            #pragma unroll
            for (int k = 0; k < 16; k++) {
                float4 y4 = yv4[i0 >> 2];
                float l0 = Lt[tri + c];
                float l1 = Lt[tri + (i0 + 1) + c];
                float l2 = Lt[tri + (2 * i0 + 3) + c];
                float l3 = Lt[tri + (3 * i0 + 6) + c];
                if (i0     >= c) acc += l0 * y4.x;
                if (i0 + 1 >= c) acc += l1 * y4.y;
                if (i0 + 2 >= c) acc += l2 * y4.z;
                if (i0 + 3 >= c) acc += l3 * y4.w;
                tri += 8 * i0 + 36;          // tri(i0+8) - tri(i0)
                i0  += 8;
            }
            part[t] = acc;
        }
        __syncthreads();   // B2
        if (t < 128) y2v[tl] = part[tl] + part[tl + 128];
        __syncthreads();   // B3

        // ---- w = L * y2 : partner h takes chunks of parity h ----
        {
            float acc = 0.0f;
            const float4* y24 = (const float4*)y2v;
            const int r = tl;
            const int base = r * (r + 1) / 2;
            const int cmax = r >> 2;
            for (int c4 = h; c4 <= cmax; c4 += 2) {
                const int j0 = 4 * c4;
                float4 y4 = y24[c4];
                if (j0     <= r) acc += Lt[base + j0]     * y4.x;
                if (j0 + 1 <= r) acc += Lt[base + j0 + 1] * y4.y;
                if (j0 + 2 <= r) acc += Lt[base + j0 + 2] * y4.z;
                if (j0 + 3 <= r) acc += Lt[base + j0 + 3] * y4.w;
            }
            part[t] = acc;
        }
        __syncthreads();   // B4

        // ---- alpha = <w, v_cur> (threads < 128 own w) ----
        float wacc = 0.0f, xcur = 0.0f;
        if (t < 128) {
            wacc = part[tl] + part[tl + 128];
            xcur = xv[tl];
            float s = wacc * xcur;
            #pragma unroll
            for (int o = 32; o > 0; o >>= 1) s += __shfl_down(s, o, 64);
            if (lane == 0) red[t >> 6] = s;
        }
        __syncthreads();   // B5
        if (t < 128) {
            float alpha = red[0] + red[1];
            wacc -= alpha * xcur + beta * pvf;
            float s = wacc * wacc;
            #pragma unroll
            for (int o = 32; o > 0; o >>= 1) s += __shfl_down(s, o, 64);
            if (lane == 0) red[2 + (t >> 6)] = s;
            if (t == 0) ab_out[(size_t)b * 20 + m] = alpha;
        }
        __syncthreads();   // B6
        float beta_new = sqrtf(red[2] + red[3]);
        if (t < 128) {
            pvf = xcur;
            xv[tl] = wacc / (beta_new + 1e-30f);
            if (t == 0) ab_out[(size_t)b * 20 + 10 + m] = beta_new;
        }
        beta = beta_new;
        __syncthreads();   // B7
    }
}

// ---------------------------------------------------------------------------
// Kernel 2: per-batch eigenvalues of 10x10 symmetric tridiagonal via
// DIVISION-FREE Sturm bisection (fp64 polynomial recurrence, sign changes).
// contrib[b] = max|l|^2 - min|l|^2.
// ---------------------------------------------------------------------------
__device__ inline int sturm_count(const double* a, const double* off2, double x) {
    double pm = 1.0;
    double p  = a[0] - x;
    int c = (p < 0.0);
    #pragma unroll
    for (int i = 1; i < M_L; i++) {
        double pn = (a[i] - x) * p - off2[i - 1] * pm;
        c += ((pn < 0.0) != (p < 0.0));
        // rescale to avoid overflow (signs preserved)
        double ap = fabs(pn);
        if (ap > 1e120) { pn *= 1e-120; p *= 1e-120; }
        pm = p;
        p  = pn;
    }
    return c;
}

__global__ __launch_bounds__(64) void eig_kernel(
    const float* __restrict__ ab, float* __restrict__ contrib)
{
    int b = blockIdx.x * blockDim.x + threadIdx.x;
    if (b >= BATCH) return;
    const float* p = ab + (size_t)b * 20;
    double a[M_L], off2[M_L - 1], offa[M_L - 1];
    #pragma unroll
    for (int i = 0; i < M_L; i++) a[i] = (double)p[i];
    #pragma unroll
    for (int i = 0; i < M_L - 1; i++) {
        double bb = (double)p[10 + i];
        offa[i] = fabs(bb);
        off2[i] = bb * bb;
    }
    // Gershgorin bounds
    double lo = 1e300, hi = -1e300;
    #pragma unroll
    for (int i = 0; i < M_L; i++) {
        double r = 0.0;
        if (i > 0) r += offa[i - 1];
        if (i < M_L - 1) r += offa[i];
        lo = fmin(lo, a[i] - r);
        hi = fmax(hi, a[i] + r);
    }
    // lambda_max
    double l = lo, h = hi;
    for (int it = 0; it < 50; it++) {
        double mid = 0.5 * (l + h);
        if (sturm_count(a, off2, mid) >= M_L) h = mid; else l = mid;
    }
    double lmax = 0.5 * (l + h);
    // lambda_min
    l = lo; h = hi;
    for (int it = 0; it < 50; it++) {
        double mid = 0.5 * (l + h);
        if (sturm_count(a, off2, mid) >= 1) h = mid; else l = mid;
    }
    double lmin = 0.5 * (l + h);
    double maxabs = fmax(fabs(lmax), fabs(lmin));
    // min |lambda| : smallest s with an eigenvalue in [-s, s)
    double tl = 0.0, th = maxabs;
    for (int it = 0; it < 50; it++) {
        double tm = 0.5 * (tl + th);
        int inwin = sturm_count(a, off2, tm) - sturm_count(a, off2, -tm);
        if (inwin >= 1) th = tm; else tl = tm;
    }
    double minabs = 0.5 * (tl + th);
    contrib[b] = (float)(maxabs * maxabs - minabs * minabs);
}

// ---------------------------------------------------------------------------
// Kernel 3: reduce 2048 contributions -> d_out[0] (mean)
// ---------------------------------------------------------------------------
__global__ __launch_bounds__(1024) void reduce_kernel(
    const float* __restrict__ contrib, float* __restrict__ out)
{
    __shared__ float red[16];
    int t = threadIdx.x;
    float s = contrib[t] + contrib[t + 1024];
    #pragma unroll
    for (int o = 32; o > 0; o >>= 1) s += __shfl_down(s, o, 64);
    if ((t & 63) == 0) red[t >> 6] = s;
    __syncthreads();
    if (t < 64) {
        float r = (t < 16) ? red[t] : 0.0f;
        #pragma unroll
        for (int o = 8; o > 0; o >>= 1) r += __shfl_down(r, o, 64);
        if (t == 0) out[0] = r / (float)BATCH;
    }
}

extern "C" void kernel_launch(void* const* d_in, const int* in_sizes, int n_in,
                              void* d_out, int out_size, void* d_ws, size_t ws_size,
                              hipStream_t stream) {
    const float* net_out = (const float*)d_in[0];
    const float* U1      = (const float*)d_in[1];
    const float* v       = (const float*)d_in[2];
    float* ab      = (float*)d_ws;            // BATCH*20 floats
    float* contrib = ab + (size_t)BATCH * 20; // BATCH floats

    lanczos_kernel<<<BATCH, 256, 0, stream>>>(net_out, U1, v, ab);
    eig_kernel<<<BATCH / 64, 64, 0, stream>>>(ab, contrib);
    reduce_kernel<<<1, 1024, 0, stream>>>(contrib, (float*)d_out);
}

// Round 4
// 210.558 us; speedup vs baseline: 2.7285x; 1.3835x over previous
//
#include <hip/hip_runtime.h>
#include <hip/hip_bf16.h>
#include <math.h>

#define NN 128
#define TRI 8256          // 128*129/2
#define BATCH 2048
#define M_L 10
#define KAPPA 0.276f
#define LDL 136           // padded row stride (bf16 elems) for Lsq/Msq; 272B = 16B-aligned, bank-rotating

using short8 = __attribute__((ext_vector_type(8))) short;   // 8 bf16 (4 VGPRs) MFMA A/B frag
using f32x4  = __attribute__((ext_vector_type(4))) float;   // MFMA C/D frag

static __device__ inline unsigned short f2bf(float f) {     // fp32 -> bf16 RNE
    unsigned u = __float_as_uint(f);
    return (unsigned short)((u + 0x7FFFu + ((u >> 16) & 1u)) >> 16);
}
static __device__ inline float bflo(unsigned u) { return __uint_as_float(u << 16); }
static __device__ inline float bfhi(unsigned u) { return __uint_as_float(u & 0xFFFF0000u); }

// ---------------------------------------------------------------------------
// Kernel 1: per-batch fused:  stage L(bf16) -> M = L*L^T via MFMA -> 10x
// Lanczos iterations with dense symmetric matvec on bf16 M from LDS.
// One block (256 thr = 4 waves) per batch. Writes alphas[10]+betas[10].
// ---------------------------------------------------------------------------
__global__ __launch_bounds__(256) void lanczos_kernel(
    const float* __restrict__ net_out,
    const float* __restrict__ U1,
    const float* __restrict__ v_in,
    float* __restrict__ ab_out)   // [BATCH][20]
{
    __shared__ unsigned short Lsq[128 * LDL];   // 34.0 KB  bf16 L (square, zero upper)
    __shared__ unsigned short Msq[128 * LDL];   // 34.0 KB  bf16 M = L L^T
    __shared__ float u0s[64], u1s[64];
    __shared__ __align__(16) float xv[NN];
    __shared__ __align__(16) float yv[NN];
    __shared__ __align__(16) float part[256];
    __shared__ float red[4];

    const int b = blockIdx.x;
    const int t = threadIdx.x;
    const int lane = t & 63;
    const int w = t >> 6;       // wave id 0..3

    // ---- zero Lsq (covers upper triangle + padding) ----
    {
        unsigned* z = (unsigned*)Lsq;
        for (int k = t; k < 128 * LDL / 2; k += 256) z[k] = 0u;
    }
    // ---- stage U1 ----
    if (t < 64) {
        const float2* uu = (const float2*)(U1 + (size_t)b * 128);
        float2 p = uu[t];
        u0s[t] = p.x; u1s[t] = p.y;
    }
    float vt = 0.0f;
    if (t < 128) vt = v_in[(size_t)b * NN + t];
    __syncthreads();

    // ---- fill Lsq lower triangle from packed tril (coalesced fp32 reads) ----
    {
        const float* src = net_out + (size_t)b * TRI;
        for (int idx = t; idx < TRI; idx += 256) {
            float f = src[idx];
            int r = (int)((sqrtf(8.0f * (float)idx + 1.0f) - 1.0f) * 0.5f);
            while ((r + 1) * (r + 2) / 2 <= idx) r++;
            while (r * (r + 1) / 2 > idx) r--;
            int c = idx - r * (r + 1) / 2;
            Lsq[r * LDL + c] = f2bf(f);
        }
    }
    // ---- v-norm partial (independent of Lsq) ----
    {
        float s = vt * vt;
        #pragma unroll
        for (int o = 32; o > 0; o >>= 1) s += __shfl_down(s, o, 64);
        if (lane == 0 && t < 128) red[w] = s;
    }
    __syncthreads();

    float nrm = sqrtf(red[0] + red[1]);
    if (t < 128) xv[t] = vt / nrm;

    // ---- GEMM: M = L * L^T  (16x16x32 bf16 MFMA, fp32 acc, bf16 out) ----
    // M symmetric => any C/D row/col-swap ambiguity is value-neutral.
    {
        const int m = lane & 15;       // A row / B col within tile
        const int g = lane >> 4;       // k-group (8 consecutive k per lane)
        f32x4 acc[2][8];
        #pragma unroll
        for (int bi = 0; bi < 2; bi++)
            #pragma unroll
            for (int j = 0; j < 8; j++)
                acc[bi][j] = (f32x4){0.f, 0.f, 0.f, 0.f};
        const int band0 = w, band1 = w + 4;     // each wave: 2 row-bands of 16
        #pragma unroll
        for (int kc = 0; kc < 4; kc++) {
            const int col = kc * 32 + g * 8;
            short8 a0 = *(const short8*)&Lsq[(16 * band0 + m) * LDL + col];
            short8 a1 = *(const short8*)&Lsq[(16 * band1 + m) * LDL + col];
            #pragma unroll
            for (int j = 0; j < 8; j++) {
                // B[k][n] = L[n][k]: row 16j+n, same contiguous k-chunk
                short8 bfr = *(const short8*)&Lsq[(16 * j + m) * LDL + col];
                acc[0][j] = __builtin_amdgcn_mfma_f32_16x16x32_bf16(a0, bfr, acc[0][j], 0, 0, 0);
                acc[1][j] = __builtin_amdgcn_mfma_f32_16x16x32_bf16(a1, bfr, acc[1][j], 0, 0, 0);
            }
        }
        // epilogue: C/D elem (row_c=4g+r, col_c=m) of tile (band,j); write the
        // TRANSPOSE (M symmetric) so the 4 regs pack into one ds_write_b64.
        #pragma unroll
        for (int bi = 0; bi < 2; bi++) {
            const int band = (bi == 0) ? band0 : band1;
            #pragma unroll
            for (int j = 0; j < 8; j++) {
                f32x4 a = acc[bi][j];
                ushort4 pk;
                pk.x = f2bf(a[0]); pk.y = f2bf(a[1]);
                pk.z = f2bf(a[2]); pk.w = f2bf(a[3]);
                *(ushort4*)&Msq[(16 * j + m) * LDL + 16 * band + 4 * g] = pk;
            }
        }
    }

    // dd stencil indices (used by t<128)
    const int si = t >> 4, sj = (t >> 1) & 7, ss = t & 1;
    const int ip = (si + 1) & 7, im = (si + 7) & 7;
    const int jp = (sj + 1) & 7, jm = (sj + 7) & 7;
    const int idx_ip = (ip << 4) | (sj << 1) | ss;
    const int idx_jp = (si << 4) | (jp << 1) | ss;
    const int idx_im = (im << 4) | (sj << 1) | ss;
    const int idx_jm = (si << 4) | (jm << 1) | ss;

    float pvf = 0.0f, beta = 0.0f;
    __syncthreads();   // Msq + xv ready

    for (int m_it = 0; m_it < M_L; m_it++) {
        // ---- y = dd(x) ----
        if (t < 128) {
            float x_t = xv[t];
            float hop = u0s[si * 8 + sj] * xv[idx_ip]
                      + u1s[si * 8 + sj] * xv[idx_jp]
                      + u0s[im * 8 + sj] * xv[idx_im]
                      + u1s[si * 8 + jm] * xv[idx_jm];
            yv[t] = x_t - KAPPA * hop;
        }
        __syncthreads();

        // ---- w_half = M[r][64h..64h+63] . y[64h..]  (r=t&127, h=t>>7) ----
        {
            const int r = t & 127, h = t >> 7;
            const unsigned short* Mrow = &Msq[r * LDL + h * 64];
            const float* yh = &yv[h * 64];
            float acc = 0.f;
            #pragma unroll
            for (int c = 0; c < 8; c++) {
                uint4 mv = *(const uint4*)(Mrow + c * 8);     // 8 bf16, b128, conflict-optimal
                float4 ya = *(const float4*)(yh + c * 8);     // wave-uniform -> broadcast
                float4 yb = *(const float4*)(yh + c * 8 + 4);
                acc += bflo(mv.x) * ya.x + bfhi(mv.x) * ya.y;
                acc += bflo(mv.y) * ya.z + bfhi(mv.y) * ya.w;
                acc += bflo(mv.z) * yb.x + bfhi(mv.z) * yb.y;
                acc += bflo(mv.w) * yb.z + bfhi(mv.w) * yb.w;
            }
            part[t] = acc;
        }
        __syncthreads();

        // ---- alpha = <w, v_cur> ----
        float wacc = 0.f, xcur = 0.f;
        if (t < 128) {
            wacc = part[t] + part[t + 128];
            xcur = xv[t];
            float s = wacc * xcur;
            #pragma unroll
            for (int o = 32; o > 0; o >>= 1) s += __shfl_down(s, o, 64);
            if (lane == 0) red[w] = s;
        }
        __syncthreads();
        if (t < 128) {
            float alpha = red[0] + red[1];
            wacc -= alpha * xcur + beta * pvf;
            float s = wacc * wacc;
            #pragma unroll
            for (int o = 32; o > 0; o >>= 1) s += __shfl_down(s, o, 64);
            if (lane == 0) red[2 + w] = s;
            if (t == 0) ab_out[(size_t)b * 20 + m_it] = alpha;
        }
        __syncthreads();
        float beta_new = sqrtf(red[2] + red[3]);
        if (t < 128) {
            pvf = xcur;
            xv[t] = wacc / (beta_new + 1e-30f);
            if (t == 0) ab_out[(size_t)b * 20 + 10 + m_it] = beta_new;
        }
        beta = beta_new;
        __syncthreads();
    }
}

// ---------------------------------------------------------------------------
// Kernel 2: eigen-extremes of 10x10 sym tridiagonal, ONE WAVE PER BATCH.
// 65-section: 64 lanes evaluate 64 Sturm points/round, ballot picks bracket.
// 4 rounds = 65^4 ~ 1.8e7 interval shrink. Division-free fp64 recurrence
// (sign-change count) -- verified exact vs numpy in R2/R3.
// ---------------------------------------------------------------------------
__device__ inline int sturm_count10(const double* a, const double* off2, double x) {
    double pm = 1.0;
    double p  = a[0] - x;
    int c = (p < 0.0);
    #pragma unroll
    for (int i = 1; i < M_L; i++) {
        double pn = (a[i] - x) * p - off2[i - 1] * pm;
        c += ((pn < 0.0) != (p < 0.0));
        if (fabs(pn) > 1e150) { pn *= 1e-150; p *= 1e-150; }
        pm = p; p = pn;
    }
    return c;
}

// smallest x in (lo,hi] with count(x) >= K   (count monotone in x)
__device__ inline double msect_smallest(const double* a, const double* off2,
                                        double lo, double hi, int K, int lane) {
    for (int round = 0; round < 4; round++) {
        double wdt = (hi - lo) * (1.0 / 65.0);
        double x = lo + wdt * (double)(lane + 1);
        int cnt = sturm_count10(a, off2, x);
        unsigned long long mask = __ballot(cnt >= K);
        if (mask == 0ULL) {
            lo = lo + wdt * 64.0;
        } else {
            int p = __ffsll(mask) - 1;
            hi = lo + wdt * (double)(p + 1);
            if (p > 0) lo = lo + wdt * (double)p;
        }
    }
    return 0.5 * (lo + hi);
}

// smallest s in (0,maxabs] with an eigenvalue in [-s, s)
__device__ inline double msect_window(const double* a, const double* off2,
                                      double maxabs, int lane) {
    double lo = 0.0, hi = maxabs;
    for (int round = 0; round < 4; round++) {
        double wdt = (hi - lo) * (1.0 / 65.0);
        double s = lo + wdt * (double)(lane + 1);
        int inwin = sturm_count10(a, off2, s) - sturm_count10(a, off2, -s);
        unsigned long long mask = __ballot(inwin >= 1);
        if (mask == 0ULL) {
            lo = lo + wdt * 64.0;
        } else {
            int p = __ffsll(mask) - 1;
            hi = lo + wdt * (double)(p + 1);
            if (p > 0) lo = lo + wdt * (double)p;
        }
    }
    return 0.5 * (lo + hi);
}

__global__ __launch_bounds__(256) void eig_kernel(
    const float* __restrict__ ab, float* __restrict__ contrib)
{
    const int lane = threadIdx.x & 63;
    const int b = blockIdx.x * 4 + (threadIdx.x >> 6);
    if (b >= BATCH) return;
    const float* p = ab + (size_t)b * 20;
    double a[M_L], off2[M_L - 1], offa[M_L - 1];
    #pragma unroll
    for (int i = 0; i < M_L; i++) a[i] = (double)p[i];
    #pragma unroll
    for (int i = 0; i < M_L - 1; i++) {
        double bb = (double)p[10 + i];
        offa[i] = fabs(bb);
        off2[i] = bb * bb;
    }
    double lo = 1e300, hi = -1e300;
    #pragma unroll
    for (int i = 0; i < M_L; i++) {
        double r = 0.0;
        if (i > 0) r += offa[i - 1];
        if (i < M_L - 1) r += offa[i];
        lo = fmin(lo, a[i] - r);
        hi = fmax(hi, a[i] + r);
    }
    double lmax = msect_smallest(a, off2, lo, hi, M_L, lane);  // count>=10 <=> x > lambda_max
    double lmin = msect_smallest(a, off2, lo, hi, 1,   lane);  // count>=1  <=> x > lambda_min
    double maxabs = fmax(fabs(lmax), fabs(lmin));
    double minabs = msect_window(a, off2, maxabs, lane);
    if (lane == 0) contrib[b] = (float)(maxabs * maxabs - minabs * minabs);
}

// ---------------------------------------------------------------------------
// Kernel 3: reduce 2048 contributions -> d_out[0] (mean)
// ---------------------------------------------------------------------------
__global__ __launch_bounds__(1024) void reduce_kernel(
    const float* __restrict__ contrib, float* __restrict__ out)
{
    __shared__ float red[16];
    int t = threadIdx.x;
    float s = contrib[t] + contrib[t + 1024];
    #pragma unroll
    for (int o = 32; o > 0; o >>= 1) s += __shfl_down(s, o, 64);
    if ((t & 63) == 0) red[t >> 6] = s;
    __syncthreads();
    if (t < 64) {
        float r = (t < 16) ? red[t] : 0.0f;
        #pragma unroll
        for (int o = 8; o > 0; o >>= 1) r += __shfl_down(r, o, 64);
        if (t == 0) out[0] = r / (float)BATCH;
    }
}

extern "C" void kernel_launch(void* const* d_in, const int* in_sizes, int n_in,
                              void* d_out, int out_size, void* d_ws, size_t ws_size,
                              hipStream_t stream) {
    const float* net_out = (const float*)d_in[0];
    const float* U1      = (const float*)d_in[1];
    const float* v       = (const float*)d_in[2];
    float* ab      = (float*)d_ws;            // BATCH*20 floats
    float* contrib = ab + (size_t)BATCH * 20; // BATCH floats

    lanczos_kernel<<<BATCH, 256, 0, stream>>>(net_out, U1, v, ab);
    eig_kernel<<<BATCH / 4, 256, 0, stream>>>(ab, contrib);
    reduce_kernel<<<1, 1024, 0, stream>>>(contrib, (float*)d_out);
}

// Round 5
// 178.164 us; speedup vs baseline: 3.2245x; 1.1818x over previous
//
#include <hip/hip_runtime.h>
#include <hip/hip_bf16.h>
#include <math.h>

#define NN 128
#define TRI 8256          // 128*129/2
#define BATCH 2048
#define M_L 10
#define KAPPA 0.276f
#define LDL 136           // padded row stride (bf16); 68 words -> 17 quads (odd) = conflict-good for row-indexed b128

using short8 = __attribute__((ext_vector_type(8))) short;   // 8 bf16 (4 VGPRs) MFMA A/B frag
using f32x4  = __attribute__((ext_vector_type(4))) float;   // MFMA C/D frag

static __device__ inline unsigned short f2bf(float f) {     // fp32 -> bf16 RNE
    unsigned u = __float_as_uint(f);
    return (unsigned short)((u + 0x7FFFu + ((u >> 16) & 1u)) >> 16);
}
static __device__ inline float bflo(unsigned u) { return __uint_as_float(u << 16); }
static __device__ inline float bfhi(unsigned u) { return __uint_as_float(u & 0xFFFF0000u); }

// ---------------------------------------------------------------------------
// Kernel 1: per-batch fused: stage L(bf16) -> M = L*L^T via MFMA (8 waves,
// 1 row-band each) -> 10 Lanczos iterations, 4 barriers/iter (deferred
// normalization: xv holds the UNNORMALIZED vector, 1/beta folded into dd).
// 512 threads/block, 2 blocks/CU (LDS) -> 16 waves/CU.
// ---------------------------------------------------------------------------
__global__ __launch_bounds__(512, 4) void lanczos_kernel(
    const float* __restrict__ net_out,
    const float* __restrict__ U1,
    const float* __restrict__ v_in,
    float* __restrict__ ab_out)   // [BATCH][20]
{
    __shared__ unsigned short Lsq[128 * LDL];   // 34.0 KB  bf16 L (zero upper)
    __shared__ unsigned short Msq[128 * LDL];   // 34.0 KB  bf16 M = L L^T
    __shared__ float u0s[64], u1s[64];
    __shared__ __align__(16) float xv[NN];      // UNNORMALIZED Lanczos vector
    __shared__ __align__(16) float yv[NN];      // normalized dd output
    __shared__ __align__(16) float part[512];
    __shared__ float red[4];

    const int b = blockIdx.x;
    const int t = threadIdx.x;
    const int lane = t & 63;
    const int w = t >> 6;       // wave id 0..7

    // ---- zero Lsq (upper triangle + padding) ----
    {
        unsigned long long* z = (unsigned long long*)Lsq;
        #pragma unroll
        for (int k = t; k < 128 * LDL * 2 / 8; k += 512) z[k] = 0ULL;
    }
    if (t < 64) {
        const float2* uu = (const float2*)(U1 + (size_t)b * 128);
        float2 p = uu[t];
        u0s[t] = p.x; u1s[t] = p.y;
    }
    float vt = 0.0f;
    if (t < 128) vt = v_in[(size_t)b * NN + t];
    __syncthreads();

    // ---- fill Lsq rows: 4 threads per row (quarters), no sqrt ----
    {
        const int r = t & 127, q = t >> 7;
        const int len = r + 1;
        const int lo = (q * len) >> 2, hi = ((q + 1) * len) >> 2;
        const float* src = net_out + (size_t)b * TRI + (r * (r + 1)) / 2;
        unsigned short* dst = &Lsq[r * LDL];
        for (int c = lo; c < hi; c++) dst[c] = f2bf(src[c]);
    }
    // ---- v-norm partials (waves 0,1) ----
    {
        float s = vt * vt;
        #pragma unroll
        for (int o = 32; o > 0; o >>= 1) s += __shfl_down(s, o, 64);
        if (lane == 0 && t < 128) red[w] = s;
    }
    __syncthreads();   // Lsq + norm ready

    float ib = 1.0f / sqrtf(red[0] + red[1]);   // 1/||v||  (current scale)
    if (t < 128) xv[t] = vt;                    // unnormalized

    // ---- GEMM: M = L * L^T  (16x16x32 bf16 MFMA; wave w owns row band w) ----
    // M symmetric => C/D row/col-swap ambiguity is value-neutral.
    {
        const int m = lane & 15;       // row within band / col within tile
        const int g = lane >> 4;       // k-group (8 consecutive k)
        f32x4 acc[8];
        #pragma unroll
        for (int j = 0; j < 8; j++) acc[j] = (f32x4){0.f, 0.f, 0.f, 0.f};
        #pragma unroll
        for (int kc = 0; kc < 4; kc++) {
            const int col = kc * 32 + g * 8;
            short8 a0 = *(const short8*)&Lsq[(16 * w + m) * LDL + col];
            #pragma unroll
            for (int j = 0; j < 8; j++) {
                short8 bfr = *(const short8*)&Lsq[(16 * j + m) * LDL + col];
                acc[j] = __builtin_amdgcn_mfma_f32_16x16x32_bf16(a0, bfr, acc[j], 0, 0, 0);
            }
        }
        // epilogue: write TRANSPOSE (M symmetric) -> 4 regs pack to one b64
        #pragma unroll
        for (int j = 0; j < 8; j++) {
            f32x4 a = acc[j];
            ushort4 pk;
            pk.x = f2bf(a[0]); pk.y = f2bf(a[1]);
            pk.z = f2bf(a[2]); pk.w = f2bf(a[3]);
            *(ushort4*)&Msq[(16 * j + m) * LDL + 16 * w + 4 * g] = pk;
        }
    }

    // dd stencil indices (threads < 128)
    const int si = t >> 4, sj = (t >> 1) & 7, ss = t & 1;
    const int ip = (si + 1) & 7, im = (si + 7) & 7;
    const int jp = (sj + 1) & 7, jm = (sj + 7) & 7;
    const int idx_ip = (ip << 4) | (sj << 1) | ss;
    const int idx_jp = (si << 4) | (jp << 1) | ss;
    const int idx_im = (im << 4) | (sj << 1) | ss;
    const int idx_jm = (si << 4) | (jm << 1) | ss;

    float pvf = 0.0f, beta = 0.0f;
    __syncthreads();   // Msq + xv ready

    for (int m_it = 0; m_it < M_L; m_it++) {
        // ---- y = dd(x_unnorm) * ib  (normalized) ----
        if (t < 128) {
            float x_t = xv[t];
            float hop = u0s[si * 8 + sj] * xv[idx_ip]
                      + u1s[si * 8 + sj] * xv[idx_jp]
                      + u0s[im * 8 + sj] * xv[idx_im]
                      + u1s[si * 8 + jm] * xv[idx_jm];
            yv[t] = ib * (x_t - KAPPA * hop);
        }
        __syncthreads();   // B1

        // ---- part = M[r][32h..32h+31] . y[32h..]  (r=t&127, h=t>>7) ----
        {
            const int r = t & 127, h = t >> 7;
            const unsigned short* Mrow = &Msq[r * LDL + 32 * h];
            const float* yh = &yv[32 * h];
            float acc = 0.f;
            #pragma unroll
            for (int c = 0; c < 4; c++) {
                uint4 mv = *(const uint4*)(Mrow + c * 8);     // 8 bf16 b128
                float4 ya = *(const float4*)(yh + c * 8);     // wave-uniform broadcast
                float4 yb = *(const float4*)(yh + c * 8 + 4);
                acc += bflo(mv.x) * ya.x + bfhi(mv.x) * ya.y;
                acc += bflo(mv.y) * ya.z + bfhi(mv.y) * ya.w;
                acc += bflo(mv.z) * yb.x + bfhi(mv.z) * yb.y;
                acc += bflo(mv.w) * yb.z + bfhi(mv.w) * yb.w;
            }
            part[t] = acc;
        }
        __syncthreads();   // B2

        // ---- combine w, alpha partials ----
        float wacc = 0.f, xcur = 0.f;
        if (t < 128) {
            wacc = part[t] + part[t + 128] + part[t + 256] + part[t + 384];
            xcur = xv[t] * ib;                    // normalized current
            float s = wacc * xcur;
            #pragma unroll
            for (int o = 32; o > 0; o >>= 1) s += __shfl_down(s, o, 64);
            if (lane == 0) red[w] = s;
        }
        __syncthreads();   // B3 (alpha ready)

        // ---- orthogonalize, write UNNORMALIZED next vector, beta partials ----
        if (t < 128) {
            float alpha = red[0] + red[1];
            wacc -= alpha * xcur + beta * pvf;
            xv[t] = wacc;                         // unnormalized v_next
            float s = wacc * wacc;
            #pragma unroll
            for (int o = 32; o > 0; o >>= 1) s += __shfl_down(s, o, 64);
            if (lane == 0) red[2 + w] = s;
            if (t == 0) ab_out[(size_t)b * 20 + m_it] = red[0] + red[1];
        }
        __syncthreads();   // B4 (beta + xv ready)

        float beta_new = sqrtf(red[2] + red[3]);
        if (t == 0) ab_out[(size_t)b * 20 + 10 + m_it] = beta_new;
        if (t < 128) pvf = xcur;
        beta = beta_new;
        ib = 1.0f / (beta_new + 1e-30f);
    }
}

// ---------------------------------------------------------------------------
// Kernel 2: eigen-extremes of 10x10 sym tridiagonal, ONE WAVE PER BATCH.
// 65-section with division-free fp64 Sturm sign counts (verified R2-R4).
// ---------------------------------------------------------------------------
__device__ inline int sturm_count10(const double* a, const double* off2, double x) {
    double pm = 1.0;
    double p  = a[0] - x;
    int c = (p < 0.0);
    #pragma unroll
    for (int i = 1; i < M_L; i++) {
        double pn = (a[i] - x) * p - off2[i - 1] * pm;
        c += ((pn < 0.0) != (p < 0.0));
        if (fabs(pn) > 1e150) { pn *= 1e-150; p *= 1e-150; }
        pm = p; p = pn;
    }
    return c;
}

__device__ inline double msect_smallest(const double* a, const double* off2,
                                        double lo, double hi, int K, int lane) {
    for (int round = 0; round < 4; round++) {
        double wdt = (hi - lo) * (1.0 / 65.0);
        double x = lo + wdt * (double)(lane + 1);
        int cnt = sturm_count10(a, off2, x);
        unsigned long long mask = __ballot(cnt >= K);
        if (mask == 0ULL) {
            lo = lo + wdt * 64.0;
        } else {
            int p = __ffsll(mask) - 1;
            hi = lo + wdt * (double)(p + 1);
            if (p > 0) lo = lo + wdt * (double)p;
        }
    }
    return 0.5 * (lo + hi);
}

__device__ inline double msect_window(const double* a, const double* off2,
                                      double maxabs, int lane) {
    double lo = 0.0, hi = maxabs;
    for (int round = 0; round < 4; round++) {
        double wdt = (hi - lo) * (1.0 / 65.0);
        double s = lo + wdt * (double)(lane + 1);
        int inwin = sturm_count10(a, off2, s) - sturm_count10(a, off2, -s);
        unsigned long long mask = __ballot(inwin >= 1);
        if (mask == 0ULL) {
            lo = lo + wdt * 64.0;
        } else {
            int p = __ffsll(mask) - 1;
            hi = lo + wdt * (double)(p + 1);
            if (p > 0) lo = lo + wdt * (double)p;
        }
    }
    return 0.5 * (lo + hi);
}

__global__ __launch_bounds__(256) void eig_kernel(
    const float* __restrict__ ab, float* __restrict__ contrib)
{
    const int lane = threadIdx.x & 63;
    const int b = blockIdx.x * 4 + (threadIdx.x >> 6);
    if (b >= BATCH) return;
    const float* p = ab + (size_t)b * 20;
    double a[M_L], off2[M_L - 1], offa[M_L - 1];
    #pragma unroll
    for (int i = 0; i < M_L; i++) a[i] = (double)p[i];
    #pragma unroll
    for (int i = 0; i < M_L - 1; i++) {
        double bb = (double)p[10 + i];
        offa[i] = fabs(bb);
        off2[i] = bb * bb;
    }
    double lo = 1e300, hi = -1e300;
    #pragma unroll
    for (int i = 0; i < M_L; i++) {
        double r = 0.0;
        if (i > 0) r += offa[i - 1];
        if (i < M_L - 1) r += offa[i];
        lo = fmin(lo, a[i] - r);
        hi = fmax(hi, a[i] + r);
    }
    double lmax = msect_smallest(a, off2, lo, hi, M_L, lane);
    double lmin = msect_smallest(a, off2, lo, hi, 1,   lane);
    double maxabs = fmax(fabs(lmax), fabs(lmin));
    double minabs = msect_window(a, off2, maxabs, lane);
    if (lane == 0) contrib[b] = (float)(maxabs * maxabs - minabs * minabs);
}

// ---------------------------------------------------------------------------
// Kernel 3: reduce 2048 contributions -> d_out[0] (mean)
// ---------------------------------------------------------------------------
__global__ __launch_bounds__(1024) void reduce_kernel(
    const float* __restrict__ contrib, float* __restrict__ out)
{
    __shared__ float red[16];
    int t = threadIdx.x;
    float s = contrib[t] + contrib[t + 1024];
    #pragma unroll
    for (int o = 32; o > 0; o >>= 1) s += __shfl_down(s, o, 64);
    if ((t & 63) == 0) red[t >> 6] = s;
    __syncthreads();
    if (t < 64) {
        float r = (t < 16) ? red[t] : 0.0f;
        #pragma unroll
        for (int o = 8; o > 0; o >>= 1) r += __shfl_down(r, o, 64);
        if (t == 0) out[0] = r / (float)BATCH;
    }
}

extern "C" void kernel_launch(void* const* d_in, const int* in_sizes, int n_in,
                              void* d_out, int out_size, void* d_ws, size_t ws_size,
                              hipStream_t stream) {
    const float* net_out = (const float*)d_in[0];
    const float* U1      = (const float*)d_in[1];
    const float* v       = (const float*)d_in[2];
    float* ab      = (float*)d_ws;            // BATCH*20 floats
    float* contrib = ab + (size_t)BATCH * 20; // BATCH floats

    lanczos_kernel<<<BATCH, 512, 0, stream>>>(net_out, U1, v, ab);
    eig_kernel<<<BATCH / 4, 256, 0, stream>>>(ab, contrib);
    reduce_kernel<<<1, 1024, 0, stream>>>(contrib, (float*)d_out);
}

// Round 6
// 147.410 us; speedup vs baseline: 3.8973x; 1.2086x over previous
//
#include <hip/hip_runtime.h>
#include <hip/hip_bf16.h>
#include <math.h>

#define NN 128
#define TRI 8256          // 128*129/2
#define BATCH 2048
#define M_L 10
#define KAPPA 0.276f
#define LDL 136           // padded row stride (fp16 elems): 17 quads/row -> rotates quad-groups, conflict-free row reads

using half8 = __attribute__((ext_vector_type(8))) _Float16;  // MFMA A/B frag (4 VGPRs)
using half2v = __attribute__((ext_vector_type(2))) _Float16;
using f32x4  = __attribute__((ext_vector_type(4))) float;    // MFMA C/D frag

static __device__ inline float dot2h(unsigned m, unsigned y, float c) {
#if __has_builtin(__builtin_amdgcn_fdot2)
    return __builtin_amdgcn_fdot2(__builtin_bit_cast(half2v, m),
                                  __builtin_bit_cast(half2v, y), c, false);
#else
    half2v a = __builtin_bit_cast(half2v, m), b = __builtin_bit_cast(half2v, y);
    return c + (float)a.x * (float)b.x + (float)a.y * (float)b.y;
#endif
}

// ---------------------------------------------------------------------------
// Kernel 1: per-batch fused: stage L(fp16) -> M = L*L^T via MFMA (acc in
// registers, M written back IN-PLACE over L after a barrier) -> 10 Lanczos
// iterations with fp16 dot2 matvec. 256 thr/block, ~37KB LDS -> 4 blocks/CU.
// ---------------------------------------------------------------------------
__global__ __launch_bounds__(256, 4) void lanczos_kernel(
    const float* __restrict__ net_out,
    const float* __restrict__ U1,
    const float* __restrict__ v_in,
    float* __restrict__ ab_out)   // [BATCH][20]
{
    __shared__ __align__(16) _Float16 Lsq[128 * LDL];  // 34KB: L, then M=L*L^T (in-place)
    __shared__ float u0s[64], u1s[64];
    __shared__ __align__(16) float xv[NN];             // UNNORMALIZED Lanczos vector
    __shared__ __align__(16) _Float16 yh[NN];          // normalized dd output (fp16)
    __shared__ __align__(16) float part[256];
    __shared__ float red[4];

    const int b = blockIdx.x;
    const int t = threadIdx.x;
    const int lane = t & 63;
    const int w = t >> 6;       // wave id 0..3

    // ---- zero Lsq (upper triangle + padding) ----
    {
        unsigned long long* z = (unsigned long long*)Lsq;
        #pragma unroll
        for (int k = t; k < 128 * LDL * 2 / 8; k += 256) z[k] = 0ULL;
    }
    if (t < 64) {
        const float2* uu = (const float2*)(U1 + (size_t)b * 128);
        float2 p = uu[t];
        u0s[t] = p.x; u1s[t] = p.y;
    }
    float vt = 0.0f;
    if (t < 128) vt = v_in[(size_t)b * NN + t];
    __syncthreads();

    // ---- fill Lsq rows: 2 threads per row (halves), no sqrt ----
    {
        const int r = t & 127, q = t >> 7;
        const int len = r + 1;
        const int lo = (q * len) >> 1, hi = ((q + 1) * len) >> 1;
        const float* src = net_out + (size_t)b * TRI + (r * (r + 1)) / 2;
        _Float16* dst = &Lsq[r * LDL];
        for (int c = lo; c < hi; c++) dst[c] = (_Float16)src[c];
    }
    // ---- v-norm partials (waves 0,1) ----
    {
        float s = vt * vt;
        #pragma unroll
        for (int o = 32; o > 0; o >>= 1) s += __shfl_down(s, o, 64);
        if (lane == 0 && t < 128) red[w] = s;
    }
    __syncthreads();   // Lsq + norm ready

    float ib = 1.0f / sqrtf(red[0] + red[1]);   // 1/||v||
    if (t < 128) xv[t] = vt;                    // unnormalized

    // ---- GEMM: M = L * L^T (16x16x32 f16 MFMA; wave w owns bands w, w+4) ----
    // Accumulate fully in registers, barrier, then write M IN-PLACE over Lsq.
    // M symmetric => C/D row/col-swap ambiguity is value-neutral.
    {
        const int m = lane & 15;       // row within band / col within tile
        const int g = lane >> 4;       // k-group (8 consecutive k)
        f32x4 acc[2][8];
        #pragma unroll
        for (int bi = 0; bi < 2; bi++)
            #pragma unroll
            for (int j = 0; j < 8; j++) acc[bi][j] = (f32x4){0.f, 0.f, 0.f, 0.f};
        const int band0 = w, band1 = w + 4;
        #pragma unroll
        for (int kc = 0; kc < 4; kc++) {
            const int col = kc * 32 + g * 8;
            half8 a0 = *(const half8*)&Lsq[(16 * band0 + m) * LDL + col];
            half8 a1 = *(const half8*)&Lsq[(16 * band1 + m) * LDL + col];
            #pragma unroll
            for (int j = 0; j < 8; j++) {
                half8 bfr = *(const half8*)&Lsq[(16 * j + m) * LDL + col];
                acc[0][j] = __builtin_amdgcn_mfma_f32_16x16x32_f16(a0, bfr, acc[0][j], 0, 0, 0);
                acc[1][j] = __builtin_amdgcn_mfma_f32_16x16x32_f16(a1, bfr, acc[1][j], 0, 0, 0);
            }
        }
        __syncthreads();   // ALL Lsq reads complete before overwrite

        // epilogue: write TRANSPOSE (M symmetric) -> 4 regs pack to one b64
        #pragma unroll
        for (int bi = 0; bi < 2; bi++) {
            const int band = (bi == 0) ? band0 : band1;
            #pragma unroll
            for (int j = 0; j < 8; j++) {
                f32x4 a = acc[bi][j];
                half2v p01 = {(_Float16)a[0], (_Float16)a[1]};
                half2v p23 = {(_Float16)a[2], (_Float16)a[3]};
                uint2 pk;
                pk.x = __builtin_bit_cast(unsigned, p01);
                pk.y = __builtin_bit_cast(unsigned, p23);
                *(uint2*)&Lsq[(16 * j + m) * LDL + 16 * band + 4 * g] = pk;
            }
        }
    }

    // dd stencil indices (threads < 128)
    const int si = t >> 4, sj = (t >> 1) & 7, ss = t & 1;
    const int ip = (si + 1) & 7, im = (si + 7) & 7;
    const int jp = (sj + 1) & 7, jm = (sj + 7) & 7;
    const int idx_ip = (ip << 4) | (sj << 1) | ss;
    const int idx_jp = (si << 4) | (jp << 1) | ss;
    const int idx_im = (im << 4) | (sj << 1) | ss;
    const int idx_jm = (si << 4) | (jm << 1) | ss;

    float pvf = 0.0f, beta = 0.0f;
    __syncthreads();   // M (in Lsq) + xv ready

    for (int m_it = 0; m_it < M_L; m_it++) {
        // ---- y = dd(x_unnorm) * ib (normalized), stored fp16 ----
        if (t < 128) {
            float x_t = xv[t];
            float hop = u0s[si * 8 + sj] * xv[idx_ip]
                      + u1s[si * 8 + sj] * xv[idx_jp]
                      + u0s[im * 8 + sj] * xv[idx_im]
                      + u1s[si * 8 + jm] * xv[idx_jm];
            yh[t] = (_Float16)(ib * (x_t - KAPPA * hop));
        }
        __syncthreads();   // B1

        // ---- part = M[r][64h..64h+63] . y[64h..]  (r=t&127, h=t>>7) ----
        {
            const int r = t & 127, h = t >> 7;
            const uint4* M4 = (const uint4*)&Lsq[r * LDL + 64 * h];
            const uint4* Y4 = (const uint4*)&yh[64 * h];   // wave-uniform -> broadcast
            float acc = 0.f;
            #pragma unroll
            for (int c = 0; c < 8; c++) {
                uint4 mv = M4[c];
                uint4 yv4 = Y4[c];
                acc = dot2h(mv.x, yv4.x, acc);
                acc = dot2h(mv.y, yv4.y, acc);
                acc = dot2h(mv.z, yv4.z, acc);
                acc = dot2h(mv.w, yv4.w, acc);
            }
            part[t] = acc;
        }
        __syncthreads();   // B2

        // ---- combine w, alpha partials ----
        float wacc = 0.f, xcur = 0.f;
        if (t < 128) {
            wacc = part[t] + part[t + 128];
            xcur = xv[t] * ib;                    // normalized current
            float s = wacc * xcur;
            #pragma unroll
            for (int o = 32; o > 0; o >>= 1) s += __shfl_down(s, o, 64);
            if (lane == 0) red[w] = s;
        }
        __syncthreads();   // B3 (alpha ready)

        // ---- orthogonalize, write UNNORMALIZED next vector, beta partials ----
        if (t < 128) {
            float alpha = red[0] + red[1];
            wacc -= alpha * xcur + beta * pvf;
            xv[t] = wacc;                         // unnormalized v_next
            float s = wacc * wacc;
            #pragma unroll
            for (int o = 32; o > 0; o >>= 1) s += __shfl_down(s, o, 64);
            if (lane == 0) red[2 + w] = s;
            if (t == 0) ab_out[(size_t)b * 20 + m_it] = red[0] + red[1];
        }
        __syncthreads();   // B4 (beta + xv ready)

        float beta_new = sqrtf(red[2] + red[3]);
        if (t == 0) ab_out[(size_t)b * 20 + 10 + m_it] = beta_new;
        if (t < 128) pvf = xcur;
        beta = beta_new;
        ib = 1.0f / (beta_new + 1e-30f);
    }
}

// ---------------------------------------------------------------------------
// Kernel 2: eigen-extremes of 10x10 sym tridiagonal, ONE WAVE PER BATCH.
// 65-section with division-free fp64 Sturm sign counts (verified R2-R5).
// ---------------------------------------------------------------------------
__device__ inline int sturm_count10(const double* a, const double* off2, double x) {
    double pm = 1.0;
    double p  = a[0] - x;
    int c = (p < 0.0);
    #pragma unroll
    for (int i = 1; i < M_L; i++) {
        double pn = (a[i] - x) * p - off2[i - 1] * pm;
        c += ((pn < 0.0) != (p < 0.0));
        if (fabs(pn) > 1e150) { pn *= 1e-150; p *= 1e-150; }
        pm = p; p = pn;
    }
    return c;
}

__device__ inline double msect_smallest(const double* a, const double* off2,
                                        double lo, double hi, int K, int lane) {
    for (int round = 0; round < 4; round++) {
        double wdt = (hi - lo) * (1.0 / 65.0);
        double x = lo + wdt * (double)(lane + 1);
        int cnt = sturm_count10(a, off2, x);
        unsigned long long mask = __ballot(cnt >= K);
        if (mask == 0ULL) {
            lo = lo + wdt * 64.0;
        } else {
            int p = __ffsll(mask) - 1;
            hi = lo + wdt * (double)(p + 1);
            if (p > 0) lo = lo + wdt * (double)p;
        }
    }
    return 0.5 * (lo + hi);
}

__device__ inline double msect_window(const double* a, const double* off2,
                                      double maxabs, int lane) {
    double lo = 0.0, hi = maxabs;
    for (int round = 0; round < 4; round++) {
        double wdt = (hi - lo) * (1.0 / 65.0);
        double s = lo + wdt * (double)(lane + 1);
        int inwin = sturm_count10(a, off2, s) - sturm_count10(a, off2, -s);
        unsigned long long mask = __ballot(inwin >= 1);
        if (mask == 0ULL) {
            lo = lo + wdt * 64.0;
        } else {
            int p = __ffsll(mask) - 1;
            hi = lo + wdt * (double)(p + 1);
            if (p > 0) lo = lo + wdt * (double)p;
        }
    }
    return 0.5 * (lo + hi);
}

__global__ __launch_bounds__(256) void eig_kernel(
    const float* __restrict__ ab, float* __restrict__ contrib)
{
    const int lane = threadIdx.x & 63;
    const int b = blockIdx.x * 4 + (threadIdx.x >> 6);
    if (b >= BATCH) return;
    const float* p = ab + (size_t)b * 20;
    double a[M_L], off2[M_L - 1], offa[M_L - 1];
    #pragma unroll
    for (int i = 0; i < M_L; i++) a[i] = (double)p[i];
    #pragma unroll
    for (int i = 0; i < M_L - 1; i++) {
        double bb = (double)p[10 + i];
        offa[i] = fabs(bb);
        off2[i] = bb * bb;
    }
    double lo = 1e300, hi = -1e300;
    #pragma unroll
    for (int i = 0; i < M_L; i++) {
        double r = 0.0;
        if (i > 0) r += offa[i - 1];
        if (i < M_L - 1) r += offa[i];
        lo = fmin(lo, a[i] - r);
        hi = fmax(hi, a[i] + r);
    }
    double lmax = msect_smallest(a, off2, lo, hi, M_L, lane);
    double lmin = msect_smallest(a, off2, lo, hi, 1,   lane);
    double maxabs = fmax(fabs(lmax), fabs(lmin));
    double minabs = msect_window(a, off2, maxabs, lane);
    if (lane == 0) contrib[b] = (float)(maxabs * maxabs - minabs * minabs);
}

// ---------------------------------------------------------------------------
// Kernel 3: reduce 2048 contributions -> d_out[0] (mean)
// ---------------------------------------------------------------------------
__global__ __launch_bounds__(1024) void reduce_kernel(
    const float* __restrict__ contrib, float* __restrict__ out)
{
    __shared__ float red[16];
    int t = threadIdx.x;
    float s = contrib[t] + contrib[t + 1024];
    #pragma unroll
    for (int o = 32; o > 0; o >>= 1) s += __shfl_down(s, o, 64);
    if ((t & 63) == 0) red[t >> 6] = s;
    __syncthreads();
    if (t < 64) {
        float r = (t < 16) ? red[t] : 0.0f;
        #pragma unroll
        for (int o = 8; o > 0; o >>= 1) r += __shfl_down(r, o, 64);
        if (t == 0) out[0] = r / (float)BATCH;
    }
}

extern "C" void kernel_launch(void* const* d_in, const int* in_sizes, int n_in,
                              void* d_out, int out_size, void* d_ws, size_t ws_size,
                              hipStream_t stream) {
    const float* net_out = (const float*)d_in[0];
    const float* U1      = (const float*)d_in[1];
    const float* v       = (const float*)d_in[2];
    float* ab      = (float*)d_ws;            // BATCH*20 floats
    float* contrib = ab + (size_t)BATCH * 20; // BATCH floats

    lanczos_kernel<<<BATCH, 256, 0, stream>>>(net_out, U1, v, ab);
    eig_kernel<<<BATCH / 4, 256, 0, stream>>>(ab, contrib);
    reduce_kernel<<<1, 1024, 0, stream>>>(contrib, (float*)d_out);
}

// Round 7
// 140.112 us; speedup vs baseline: 4.1003x; 1.0521x over previous
//
#include <hip/hip_runtime.h>
#include <hip/hip_bf16.h>
#include <math.h>

#define NN 128
#define TRI 8256          // 128*129/2
#define BATCH 2048
#define M_L 10
#define KAPPA 0.276f
#define LDL 136           // padded row stride (fp16): 17 quads/row, 16B-aligned rows

using half8  = __attribute__((ext_vector_type(8))) _Float16;  // MFMA A/B frag (4 VGPRs)
using half2v = __attribute__((ext_vector_type(2))) _Float16;
using f32x4  = __attribute__((ext_vector_type(4))) float;     // MFMA C/D frag

static __device__ inline float dot2h(unsigned m, unsigned y, float c) {
#if __has_builtin(__builtin_amdgcn_fdot2)
    return __builtin_amdgcn_fdot2(__builtin_bit_cast(half2v, m),
                                  __builtin_bit_cast(half2v, y), c, false);
#else
    half2v a = __builtin_bit_cast(half2v, m), b = __builtin_bit_cast(half2v, y);
    return c + (float)a.x * (float)b.x + (float)a.y * (float)b.y;
#endif
}

// ---------------------------------------------------------------------------
// Kernel 1: per-batch fused: coalesced stage L(fp16) -> M = L*L^T via MFMA
// (in-place over L) -> 10 Lanczos iterations at 3 barriers/iter:
//   B1: yh ready -> full-row fp16 dot2 matvec (threads<128) + fused triple
//   reduction (alpha, |z|^2, <z,p>) -> B2 -> update (alpha AND beta in one
//   segment via ||w||^2 = |z|^2 - a^2 - b(2<z,p>-b)) -> B3 -> dd.
// 256 thr/block, ~36KB LDS -> 4 blocks/CU.
// ---------------------------------------------------------------------------
__global__ __launch_bounds__(256, 4) void lanczos_kernel(
    const float* __restrict__ net_out,
    const float* __restrict__ U1,
    const float* __restrict__ v_in,
    float* __restrict__ ab_out)   // [BATCH][20]
{
    __shared__ __align__(16) _Float16 Lsq[128 * LDL];  // 34KB: L, then M=L*L^T (in-place)
    __shared__ float u0s[64], u1s[64];
    __shared__ __align__(16) float xv[NN];             // normalized Lanczos vector (fp32)
    __shared__ __align__(16) _Float16 yh[NN];          // dd output (fp16)
    __shared__ float red[6];

    const int b = blockIdx.x;
    const int t = threadIdx.x;
    const int lane = t & 63;
    const int w = t >> 6;       // wave id 0..3

    // ---- zero Lsq (upper triangle + padding) ----
    {
        unsigned long long* z = (unsigned long long*)Lsq;
        #pragma unroll
        for (int k = t; k < 128 * LDL * 2 / 8; k += 256) z[k] = 0ULL;
    }
    if (t < 64) {
        const float2* uu = (const float2*)(U1 + (size_t)b * 128);
        float2 p = uu[t];
        u0s[t] = p.x; u1s[t] = p.y;
    }
    float vt = 0.0f;
    if (t < 128) vt = v_in[(size_t)b * NN + t];
    __syncthreads();

    // ---- stage L: COALESCED float4 reads of packed tril, scatter fp16 ----
    {
        const float4* src4 = (const float4*)(net_out + (size_t)b * TRI);
        for (int q = t; q < TRI / 4; q += 256) {   // 2064 quads
            float4 f = src4[q];
            int e = 4 * q;
            int r = (int)((sqrtf(8.0f * (float)e + 1.0f) - 1.0f) * 0.5f);
            while ((r + 1) * (r + 2) / 2 <= e) r++;
            while (r * (r + 1) / 2 > e) r--;
            int c = e - r * (r + 1) / 2;
            Lsq[r * LDL + c] = (_Float16)f.x;
            c++; if (c > r) { r++; c = 0; }
            Lsq[r * LDL + c] = (_Float16)f.y;
            c++; if (c > r) { r++; c = 0; }
            Lsq[r * LDL + c] = (_Float16)f.z;
            c++; if (c > r) { r++; c = 0; }
            Lsq[r * LDL + c] = (_Float16)f.w;
        }
    }
    // ---- v-norm partials (waves 0,1) ----
    {
        float s = vt * vt;
        #pragma unroll
        for (int o = 32; o > 0; o >>= 1) s += __shfl_down(s, o, 64);
        if (lane == 0 && t < 128) red[w] = s;
    }
    __syncthreads();   // Lsq + norm ready

    float xcur = 0.0f;
    if (t < 128) {
        float nrm = sqrtf(red[0] + red[1]);
        xcur = vt / nrm;
        xv[t] = xcur;
    }

    // ---- GEMM: M = L * L^T (16x16x32 f16 MFMA; wave w owns bands w, w+4) ----
    // Accumulate in registers, barrier, write M IN-PLACE over Lsq.
    // M symmetric => C/D row/col-swap ambiguity is value-neutral.
    {
        const int m = lane & 15;       // row within band / col within tile
        const int g = lane >> 4;       // k-group (8 consecutive k)
        f32x4 acc[2][8];
        #pragma unroll
        for (int bi = 0; bi < 2; bi++)
            #pragma unroll
            for (int j = 0; j < 8; j++) acc[bi][j] = (f32x4){0.f, 0.f, 0.f, 0.f};
        const int band0 = w, band1 = w + 4;
        #pragma unroll
        for (int kc = 0; kc < 4; kc++) {
            const int col = kc * 32 + g * 8;
            half8 a0 = *(const half8*)&Lsq[(16 * band0 + m) * LDL + col];
            half8 a1 = *(const half8*)&Lsq[(16 * band1 + m) * LDL + col];
            #pragma unroll
            for (int j = 0; j < 8; j++) {
                half8 bfr = *(const half8*)&Lsq[(16 * j + m) * LDL + col];
                acc[0][j] = __builtin_amdgcn_mfma_f32_16x16x32_f16(a0, bfr, acc[0][j], 0, 0, 0);
                acc[1][j] = __builtin_amdgcn_mfma_f32_16x16x32_f16(a1, bfr, acc[1][j], 0, 0, 0);
            }
        }
        __syncthreads();   // ALL Lsq reads complete before overwrite

        #pragma unroll
        for (int bi = 0; bi < 2; bi++) {
            const int band = (bi == 0) ? band0 : band1;
            #pragma unroll
            for (int j = 0; j < 8; j++) {
                f32x4 a = acc[bi][j];
                half2v p01 = {(_Float16)a[0], (_Float16)a[1]};
                half2v p23 = {(_Float16)a[2], (_Float16)a[3]};
                uint2 pk;
                pk.x = __builtin_bit_cast(unsigned, p01);
                pk.y = __builtin_bit_cast(unsigned, p23);
                *(uint2*)&Lsq[(16 * j + m) * LDL + 16 * band + 4 * g] = pk;
            }
        }
    }

    // dd stencil indices (threads < 128)
    const int si = t >> 4, sj = (t >> 1) & 7, ss = t & 1;
    const int ip = (si + 1) & 7, im = (si + 7) & 7;
    const int jp = (sj + 1) & 7, jm = (sj + 7) & 7;
    const int idx_ip = (ip << 4) | (sj << 1) | ss;
    const int idx_jp = (si << 4) | (jp << 1) | ss;
    const int idx_im = (im << 4) | (sj << 1) | ss;
    const int idx_jm = (si << 4) | (jm << 1) | ss;

    float pvf = 0.0f, beta = 0.0f;
    __syncthreads();   // M (in Lsq) + xv ready

    for (int m_it = 0; m_it < M_L; m_it++) {
        // ---- y = dd(x) (fp16) ----
        if (t < 128) {
            float hop = u0s[si * 8 + sj] * xv[idx_ip]
                      + u1s[si * 8 + sj] * xv[idx_jp]
                      + u0s[im * 8 + sj] * xv[idx_im]
                      + u1s[si * 8 + jm] * xv[idx_jm];
            yh[t] = (_Float16)(xcur - KAPPA * hop);
        }
        __syncthreads();   // B1 (yh ready)

        // ---- z = M[t][:] . y  (full row, threads<128) + triple reduction ----
        float z = 0.0f;
        if (t < 128) {
            const uint4* M4 = (const uint4*)&Lsq[t * LDL];
            const uint4* Y4 = (const uint4*)yh;   // wave-uniform -> broadcast
            float acc = 0.f;
            #pragma unroll
            for (int c = 0; c < 16; c++) {
                uint4 mv = M4[c];
                uint4 yv4 = Y4[c];
                acc = dot2h(mv.x, yv4.x, acc);
                acc = dot2h(mv.y, yv4.y, acc);
                acc = dot2h(mv.z, yv4.z, acc);
                acc = dot2h(mv.w, yv4.w, acc);
            }
            z = acc;
            float s1 = z * xcur;   // -> alpha
            float s2 = z * z;      // -> |z|^2
            float s3 = z * pvf;    // -> <z, p>
            #pragma unroll
            for (int o = 32; o > 0; o >>= 1) {
                s1 += __shfl_down(s1, o, 64);
                s2 += __shfl_down(s2, o, 64);
                s3 += __shfl_down(s3, o, 64);
            }
            if (lane == 0) { red[w] = s1; red[2 + w] = s2; red[4 + w] = s3; }
        }
        __syncthreads();   // B2 (reductions ready)

        // ---- update: alpha AND beta in one segment ----
        if (t < 128) {
            float alpha = red[0] + red[1];
            float z2    = red[2] + red[3];
            float zp    = red[4] + red[5];
            float b2 = z2 - alpha * alpha - beta * (2.0f * zp - beta);
            float beta_new = sqrtf(fmaxf(b2, 0.0f));
            float wv = z - alpha * xcur - beta * pvf;
            float xn = wv / (beta_new + 1e-30f);
            pvf = xcur;
            xcur = xn;
            xv[t] = xn;
            beta = beta_new;
            if (t == 0) {
                ab_out[(size_t)b * 20 + m_it]      = alpha;
                ab_out[(size_t)b * 20 + 10 + m_it] = beta_new;
            }
        }
        __syncthreads();   // B3 (xv ready for next dd)
    }
}

// ---------------------------------------------------------------------------
// Kernel 2: eigen-extremes of 10x10 sym tridiagonal, ONE WAVE PER BATCH.
// 65-section with division-free fp64 Sturm sign counts (verified R2-R6).
// ---------------------------------------------------------------------------
__device__ inline int sturm_count10(const double* a, const double* off2, double x) {
    double pm = 1.0;
    double p  = a[0] - x;
    int c = (p < 0.0);
    #pragma unroll
    for (int i = 1; i < M_L; i++) {
        double pn = (a[i] - x) * p - off2[i - 1] * pm;
        c += ((pn < 0.0) != (p < 0.0));
        if (fabs(pn) > 1e150) { pn *= 1e-150; p *= 1e-150; }
        pm = p; p = pn;
    }
    return c;
}

__device__ inline double msect_smallest(const double* a, const double* off2,
                                        double lo, double hi, int K, int lane) {
    for (int round = 0; round < 4; round++) {
        double wdt = (hi - lo) * (1.0 / 65.0);
        double x = lo + wdt * (double)(lane + 1);
        int cnt = sturm_count10(a, off2, x);
        unsigned long long mask = __ballot(cnt >= K);
        if (mask == 0ULL) {
            lo = lo + wdt * 64.0;
        } else {
            int p = __ffsll(mask) - 1;
            hi = lo + wdt * (double)(p + 1);
            if (p > 0) lo = lo + wdt * (double)p;
        }
    }
    return 0.5 * (lo + hi);
}

__device__ inline double msect_window(const double* a, const double* off2,
                                      double maxabs, int lane) {
    double lo = 0.0, hi = maxabs;
    for (int round = 0; round < 4; round++) {
        double wdt = (hi - lo) * (1.0 / 65.0);
        double s = lo + wdt * (double)(lane + 1);
        int inwin = sturm_count10(a, off2, s) - sturm_count10(a, off2, -s);
        unsigned long long mask = __ballot(inwin >= 1);
        if (mask == 0ULL) {
            lo = lo + wdt * 64.0;
        } else {
            int p = __ffsll(mask) - 1;
            hi = lo + wdt * (double)(p + 1);
            if (p > 0) lo = lo + wdt * (double)p;
        }
    }
    return 0.5 * (lo + hi);
}

__global__ __launch_bounds__(256) void eig_kernel(
    const float* __restrict__ ab, float* __restrict__ contrib)
{
    const int lane = threadIdx.x & 63;
    const int b = blockIdx.x * 4 + (threadIdx.x >> 6);
    if (b >= BATCH) return;
    const float* p = ab + (size_t)b * 20;
    double a[M_L], off2[M_L - 1], offa[M_L - 1];
    #pragma unroll
    for (int i = 0; i < M_L; i++) a[i] = (double)p[i];
    #pragma unroll
    for (int i = 0; i < M_L - 1; i++) {
        double bb = (double)p[10 + i];
        offa[i] = fabs(bb);
        off2[i] = bb * bb;
    }
    double lo = 1e300, hi = -1e300;
    #pragma unroll
    for (int i = 0; i < M_L; i++) {
        double r = 0.0;
        if (i > 0) r += offa[i - 1];
        if (i < M_L - 1) r += offa[i];
        lo = fmin(lo, a[i] - r);
        hi = fmax(hi, a[i] + r);
    }
    double lmax = msect_smallest(a, off2, lo, hi, M_L, lane);
    double lmin = msect_smallest(a, off2, lo, hi, 1,   lane);
    double maxabs = fmax(fabs(lmax), fabs(lmin));
    double minabs = msect_window(a, off2, maxabs, lane);
    if (lane == 0) contrib[b] = (float)(maxabs * maxabs - minabs * minabs);
}

// ---------------------------------------------------------------------------
// Kernel 3: reduce 2048 contributions -> d_out[0] (mean)
// ---------------------------------------------------------------------------
__global__ __launch_bounds__(1024) void reduce_kernel(
    const float* __restrict__ contrib, float* __restrict__ out)
{
    __shared__ float red[16];
    int t = threadIdx.x;
    float s = contrib[t] + contrib[t + 1024];
    #pragma unroll
    for (int o = 32; o > 0; o >>= 1) s += __shfl_down(s, o, 64);
    if ((t & 63) == 0) red[t >> 6] = s;
    __syncthreads();
    if (t < 64) {
        float r = (t < 16) ? red[t] : 0.0f;
        #pragma unroll
        for (int o = 8; o > 0; o >>= 1) r += __shfl_down(r, o, 64);
        if (t == 0) out[0] = r / (float)BATCH;
    }
}

extern "C" void kernel_launch(void* const* d_in, const int* in_sizes, int n_in,
                              void* d_out, int out_size, void* d_ws, size_t ws_size,
                              hipStream_t stream) {
    const float* net_out = (const float*)d_in[0];
    const float* U1      = (const float*)d_in[1];
    const float* v       = (const float*)d_in[2];
    float* ab      = (float*)d_ws;            // BATCH*20 floats
    float* contrib = ab + (size_t)BATCH * 20; // BATCH floats

    lanczos_kernel<<<BATCH, 256, 0, stream>>>(net_out, U1, v, ab);
    eig_kernel<<<BATCH / 4, 256, 0, stream>>>(ab, contrib);
    reduce_kernel<<<1, 1024, 0, stream>>>(contrib, (float*)d_out);
}